// Round 7
// baseline (161.875 us; speedup 1.0000x reference)
//
#include <hip/hip_runtime.h>
#include <hip/hip_bf16.h>
#include <math.h>

#define N_NODES 50000
#define N_EDGES 1600000
#define IN_DIM  128
#define HC      64   // H*C
#define NH      4    // heads
#define SLOTS   72   // CSR slots per node; true max degree ~58 (Poisson 32+5.5s)
#define BSHIFT  6    // bucket = dst >> 6 : 64 nodes per bucket
#define BNODES  64
#define NB      782  // 782 * 64 = 50048 >= 50000
#define BCAP    2432 // per-bucket capacity: Poisson mean 2048 + ~8.5 sigma, mult of 4
#define BIN_BLOCKS 500
#define BIN_G   800  // int4 edge-groups per bin block: 500*800*4 = 1.6M exactly
#define GEMM_BLOCKS 391   // 391*128 = 50048 nodes
#define FAT_GRID (GEMM_BLOCKS + BIN_BLOCKS)   // 891; all co-resident (4 blk/CU)
#define GEMM_LDS 33792    // 64*132*4

// ---------------------------------------------------------------- fat: gemm + count
// R7: bin_count is INDEPENDENT of gemm, so it rides along as extra blocks
// (891 total, all fit on-chip at once: LDS 4x33.8K=135K<160K, 2048 thr/CU).
// Count's ~9us serial slot disappears under gemm; one dispatch gap saved.
__global__ __launch_bounds__(512) void gemm_count_kernel(
    const float* __restrict__ x, const float* __restrict__ W,
    const float* __restrict__ att_src, const float* __restrict__ att_dst,
    const int* __restrict__ ei,
    __hip_bfloat16* __restrict__ xp, float* __restrict__ a_src,
    float* __restrict__ a_dst, int* __restrict__ counts) {
    extern __shared__ char smraw[];
    int tid = (int)threadIdx.x;
    int bx  = (int)blockIdx.x;

    if (bx >= GEMM_BLOCKS) {
        // ---- count role (500 blocks)
        int cb = bx - GEMM_BLOCKS;
        int* lcount = (int*)smraw;
        for (int j = tid; j < NB; j += 512) lcount[j] = 0;
        __syncthreads();
        const int4* dp = (const int4*)(ei + N_EDGES);
        int g0 = cb * BIN_G;
#pragma unroll
        for (int it = 0; it < 2; ++it) {
            int gi = it * 512 + tid;
            if (gi < BIN_G) {
                int4 dv = dp[g0 + gi];
                atomicAdd(&lcount[dv.x >> BSHIFT], 1);
                atomicAdd(&lcount[dv.y >> BSHIFT], 1);
                atomicAdd(&lcount[dv.z >> BSHIFT], 1);
                atomicAdd(&lcount[dv.w >> BSHIFT], 1);
            }
        }
        __syncthreads();
        for (int j = tid; j < NB; j += 512)
            counts[cb * NB + j] = lcount[j];      // coalesced row write
        return;
    }

    // ---- gemm role (391 blocks), proven body
    int gb = bx;
    float* Wl = (float*)smraw;
    const float4* W4 = (const float4*)W;
#pragma unroll
    for (int j = 0; j < 4; ++j) {        // 2048 float4 / 512 threads
        int f = j * 512 + tid;
        int c = f >> 5, k4 = f & 31;
        *(float4*)&Wl[c * 132 + k4 * 4] = W4[f];
    }
    __syncthreads();

    int l = tid & 63, w = tid >> 6, q = l >> 4, i = l & 15;
    int n0 = gb * 128 + w * 16 + q * 4;
    int nj[4];
#pragma unroll
    for (int j = 0; j < 4; ++j) {
        int n = n0 + j;
        nj[j] = (n < N_NODES) ? n : N_NODES - 1;   // clamp loads; stores guarded
    }
    const float* wlp = Wl + i * 132;               // rows i,i+16,i+32,i+48
    float4 acc[4] = {{0,0,0,0},{0,0,0,0},{0,0,0,0},{0,0,0,0}};
    float4 xr[4], xn[4];
#pragma unroll
    for (int j = 0; j < 4; ++j) xr[j] = *(const float4*)(x + (size_t)nj[j] * IN_DIM);
#pragma unroll 2
    for (int k0 = 0; k0 < IN_DIM; k0 += 4) {
        if (k0 + 4 < IN_DIM) {
#pragma unroll
            for (int j = 0; j < 4; ++j)
                xn[j] = *(const float4*)(x + (size_t)nj[j] * IN_DIM + k0 + 4);
        }
        float4 wl0 = *(const float4*)(wlp + 0 * 16 * 132 + k0);
        float4 wl1 = *(const float4*)(wlp + 1 * 16 * 132 + k0);
        float4 wl2 = *(const float4*)(wlp + 2 * 16 * 132 + k0);
        float4 wl3 = *(const float4*)(wlp + 3 * 16 * 132 + k0);
#pragma unroll
        for (int j = 0; j < 4; ++j) {
            float4 xv = xr[j];
            acc[j].x = fmaf(xv.x, wl0.x, fmaf(xv.y, wl0.y, fmaf(xv.z, wl0.z, fmaf(xv.w, wl0.w, acc[j].x))));
            acc[j].y = fmaf(xv.x, wl1.x, fmaf(xv.y, wl1.y, fmaf(xv.z, wl1.z, fmaf(xv.w, wl1.w, acc[j].y))));
            acc[j].z = fmaf(xv.x, wl2.x, fmaf(xv.y, wl2.y, fmaf(xv.z, wl2.z, fmaf(xv.w, wl2.w, acc[j].z))));
            acc[j].w = fmaf(xv.x, wl3.x, fmaf(xv.y, wl3.y, fmaf(xv.z, wl3.z, fmaf(xv.w, wl3.w, acc[j].w))));
        }
#pragma unroll
        for (int j = 0; j < 4; ++j) xr[j] = xn[j];
    }

    float a_s0 = att_src[i], a_s1 = att_src[16 + i], a_s2 = att_src[32 + i], a_s3 = att_src[48 + i];
    float a_d0 = att_dst[i], a_d1 = att_dst[16 + i], a_d2 = att_dst[32 + i], a_d3 = att_dst[48 + i];
#pragma unroll
    for (int j = 0; j < 4; ++j) {
        int n = n0 + j;
        if (n < N_NODES) {                          // quarter-uniform guard
            __hip_bfloat16* xw = xp + (size_t)n * HC;
            xw[i]      = __float2bfloat16(acc[j].x);
            xw[16 + i] = __float2bfloat16(acc[j].y);
            xw[32 + i] = __float2bfloat16(acc[j].z);
            xw[48 + i] = __float2bfloat16(acc[j].w);
            float4 ps, pd;
            ps.x = acc[j].x * a_s0; ps.y = acc[j].y * a_s1;
            ps.z = acc[j].z * a_s2; ps.w = acc[j].w * a_s3;
            pd.x = acc[j].x * a_d0; pd.y = acc[j].y * a_d1;
            pd.z = acc[j].z * a_d2; pd.w = acc[j].w * a_d3;
#pragma unroll
            for (int off = 1; off < 16; off <<= 1) {  // stays within quarter
                ps.x += __shfl_xor(ps.x, off, 64); ps.y += __shfl_xor(ps.y, off, 64);
                ps.z += __shfl_xor(ps.z, off, 64); ps.w += __shfl_xor(ps.w, off, 64);
                pd.x += __shfl_xor(pd.x, off, 64); pd.y += __shfl_xor(pd.y, off, 64);
                pd.z += __shfl_xor(pd.z, off, 64); pd.w += __shfl_xor(pd.w, off, 64);
            }
            if (i == 0) {
                *(float4*)(a_src + n * NH) = ps;
                *(float4*)(a_dst + n * NH) = pd;
            }
        }
    }
}

// ---------------------------------------------------------------- bin scan
// One block per bucket: exclusive scan of counts[0..499][j]. 512-thread
// Hillis-Steele (9 rounds). Writes base rows + bucket total.
__global__ __launch_bounds__(512) void bin_scan_kernel(
    const int* __restrict__ counts, int* __restrict__ base,
    int* __restrict__ btot) {
    __shared__ int sc[512];
    int j = (int)blockIdx.x, t = (int)threadIdx.x;
    int v = (t < BIN_BLOCKS) ? counts[t * NB + j] : 0;
    sc[t] = v;
    __syncthreads();
#pragma unroll
    for (int off = 1; off < 512; off <<= 1) {
        int u = (t >= off) ? sc[t - off] : 0;
        __syncthreads();
        sc[t] += u;
        __syncthreads();
    }
    if (t < BIN_BLOCKS) base[t * NB + j] = sc[t] - v;   // exclusive
    if (t == BIN_BLOCKS - 1) btot[j] = sc[t];           // bucket total
}

// ---------------------------------------------------------------- bin append
// 500 blocks (~2/CU; R6's 250 was 0.98/CU and latency-starved).
__global__ __launch_bounds__(512) void bin_append_kernel(
    const int* __restrict__ ei, const int* __restrict__ base,
    unsigned int* __restrict__ barr) {
    __shared__ int lbase[NB], lcnt[NB];
    int tid = (int)threadIdx.x;
    int bx  = (int)blockIdx.x;
    for (int j = tid; j < NB; j += 512) {
        lbase[j] = base[bx * NB + j];             // coalesced row read
        lcnt[j]  = 0;
    }
    __syncthreads();
    const int4* sp = (const int4*)ei;
    const int4* dp = (const int4*)(ei + N_EDGES);
    int g0 = bx * BIN_G;
#pragma unroll
    for (int it = 0; it < 2; ++it) {
        int gi = it * 512 + tid;
        if (gi < BIN_G) {
            int4 sv = sp[g0 + gi];
            int4 dv = dp[g0 + gi];
            int s[4] = {sv.x, sv.y, sv.z, sv.w};
            int d[4] = {dv.x, dv.y, dv.z, dv.w};
#pragma unroll
            for (int u = 0; u < 4; ++u) {
                int bk = d[u] >> BSHIFT;
                int lp = atomicAdd(&lcnt[bk], 1);
                int pos = lbase[bk] + lp;
                if (pos < BCAP)   // Poisson(2048)>2432 is ~1e-15; never corrupt
                    barr[(size_t)bk * BCAP + pos] =
                        (unsigned)s[u] | ((unsigned)(d[u] & (BNODES - 1)) << 20);
            }
        }
    }
}

// ---------------------------------------------------------------- gather
// Phase B now depth-1 prefetches the next k-iteration's score chain
// (shfl -> a_src gather) so its L2 latency hides under the current FMA
// block. t8 stays in-iteration (VGPR budget). 8 dst/wave, 8 lanes/dst,
// 8 channels/lane.
__global__ __launch_bounds__(512) void fused_gather_kernel(
    const unsigned int* __restrict__ barr, const int* __restrict__ btot,
    const float* __restrict__ a_src, const float* __restrict__ a_dst,
    const __hip_bfloat16* __restrict__ xp, const float* __restrict__ bias,
    float* __restrict__ out) {
    __shared__ int lcsr[BNODES * SLOTS];   // 18432 B
    __shared__ int deg[BNODES];
    int b = blockIdx.x, tid = (int)threadIdx.x;
    if (tid < BNODES) deg[tid] = 0;
    __syncthreads();
    int n = btot[b];
    n = (n < BCAP) ? n : BCAP;
    const unsigned int* src = barr + (size_t)b * BCAP;

    for (int i0 = 0; i0 < n; i0 += 2048) {
        int ibase = i0 + tid * 4;
        unsigned v[4]; bool val[4]; int dp[4], pos[4];
        if (ibase < n) {
            uint4 r = *(const uint4*)(src + ibase);   // BCAP mult of 4, 16B aligned
            v[0] = r.x; v[1] = r.y; v[2] = r.z; v[3] = r.w;
        } else { v[0] = v[1] = v[2] = v[3] = 0u; }
#pragma unroll
        for (int u = 0; u < 4; ++u) {
            val[u] = (ibase + u) < n;
            dp[u] = (int)(v[u] >> 20);                // 0..63
            if (val[u]) pos[u] = atomicAdd(&deg[dp[u]], 1);
        }
#pragma unroll
        for (int u = 0; u < 4; ++u)
            if (val[u] && pos[u] < SLOTS)
                lcsr[dp[u] * SLOTS + pos[u]] = (int)(v[u] & 0xFFFFF);
    }
    __syncthreads();

    int l = tid & 63;
    int w = tid >> 6;                 // wave 0..7
    int g = l >> 3;                   // group 0..7 (8 lanes each)
    int i = l & 7;                    // lane within group
    int h = i >> 1;                   // head of this lane's 8 channels
    int dl = w * 8 + g;               // local node 0..63
    int dst = (b << BSHIFT) + dl;     // up to 50047; guarded below
    int dg = deg[dl];
    dg = (dg < SLOTS) ? dg : SLOTS;
    int dstc = (dst < N_NODES) ? dst : 0;   // clamp: a_dst read stays in-bounds
    float adh = a_dst[dstc * NH + h];

    int sreg[9];
#pragma unroll
    for (int k = 0; k < 9; ++k) sreg[k] = lcsr[dl * SLOTS + k * 8 + i];

    const unsigned short* xpi = (const unsigned short*)xp + 8 * i;  // lane's 8 ch
    const float* asrch = a_src + h;
    int gsel = l & 56;                // group base lane for shfl
    float a0=0,a1=0,a2=0,a3=0,a4=0,a5=0,a6=0,a7=0;
    float dsum = 0.f;

    int s8a[8]; float g8a[8];
    if (dg > 0) {                     // prologue: k=0 score chain
        int cnt0 = dg;
#pragma unroll
        for (int u = 0; u < 8; ++u) {
            int raw = __shfl(sreg[0], gsel | u, 64);
            s8a[u] = (u < cnt0) ? raw : 0;
        }
#pragma unroll
        for (int u = 0; u < 8; ++u) g8a[u] = asrch[s8a[u] * NH];
    }

#pragma unroll
    for (int k = 0; k < 9; ++k) {
        if (dg > k * 8) {             // group-uniform; exec-mask guard
            int cnt = dg - k * 8;
            uint4 t8[8];
#pragma unroll
            for (int u = 0; u < 8; ++u)
                t8[u] = *(const uint4*)(xpi + (size_t)s8a[u] * HC);
            int s8n[8]; float g8n[8];
            bool nx = (k + 1 < 9) && (dg > (k + 1) * 8);
            if (nx) {                 // prefetch next k's score chain
                int cntn = dg - (k + 1) * 8;
#pragma unroll
                for (int u = 0; u < 8; ++u) {
                    int raw = __shfl(sreg[k + 1], gsel | u, 64);
                    s8n[u] = (u < cntn) ? raw : 0;
                }
#pragma unroll
                for (int u = 0; u < 8; ++u) g8n[u] = asrch[s8n[u] * NH];
            }
#pragma unroll
            for (int u = 0; u < 8; ++u) {
                float e = g8a[u] + adh;
                e = fmaxf(e, 0.2f * e);
                float wv = (u < cnt) ? __expf(e) : 0.f;
                dsum += wv;
                uint4 t = t8[u];
                a0 = fmaf(wv, __uint_as_float(t.x << 16),          a0);
                a1 = fmaf(wv, __uint_as_float(t.x & 0xffff0000u),  a1);
                a2 = fmaf(wv, __uint_as_float(t.y << 16),          a2);
                a3 = fmaf(wv, __uint_as_float(t.y & 0xffff0000u),  a3);
                a4 = fmaf(wv, __uint_as_float(t.z << 16),          a4);
                a5 = fmaf(wv, __uint_as_float(t.z & 0xffff0000u),  a5);
                a6 = fmaf(wv, __uint_as_float(t.w << 16),          a6);
                a7 = fmaf(wv, __uint_as_float(t.w & 0xffff0000u),  a7);
            }
            if (nx) {
#pragma unroll
                for (int u = 0; u < 8; ++u) { s8a[u] = s8n[u]; g8a[u] = g8n[u]; }
            }
        }
    }
    if (dst < N_NODES) {
        float inv = 1.f / (dsum + 1e-16f);
        float4 b0 = *(const float4*)(bias + 8 * i);
        float4 b1 = *(const float4*)(bias + 8 * i + 4);
        float4 o0, o1;
        o0.x = a0 * inv + b0.x; o0.y = a1 * inv + b0.y;
        o0.z = a2 * inv + b0.z; o0.w = a3 * inv + b0.w;
        o1.x = a4 * inv + b1.x; o1.y = a5 * inv + b1.y;
        o1.z = a6 * inv + b1.z; o1.w = a7 * inv + b1.w;
        float* op = out + (size_t)dst * HC + 8 * i;
        *(float4*)op = o0;
        *(float4*)(op + 4) = o1;
    }
}

// ---------------------------------------------------------------- launcher
extern "C" void kernel_launch(void* const* d_in, const int* in_sizes, int n_in,
                              void* d_out, int out_size, void* d_ws, size_t ws_size,
                              hipStream_t stream) {
    const float* x       = (const float*)d_in[0];
    const int*   ei      = (const int*)d_in[1];   // [2][E]
    const float* W       = (const float*)d_in[2];
    const float* att_src = (const float*)d_in[3];
    const float* att_dst = (const float*)d_in[4];
    const float* bias    = (const float*)d_in[5];
    float* out = (float*)d_out;

    char* ws = (char*)d_ws;
    __hip_bfloat16* xp      = (__hip_bfloat16*)(ws);   //  6,400,000 B
    float*          a_srcv  = (float*)(ws + 6400000);  //    800,000 B
    float*          a_dstv  = (float*)(ws + 7200000);  //    800,000 B
    int*            btot    = (int*)  (ws + 8000000);  //      3,128 B
    unsigned int*   barr    = (unsigned int*)(ws + 8016384); // 782*2432*4 = 7,607,296 B
    int*            counts  = (int*)  (ws + 15700000); //  1,564,000 B (500*782)
    int*            basem   = (int*)  (ws + 17300000); //  1,564,000 B
    // total ~18.9 MB; no memsets (all coordination rewritten each iter)

    gemm_count_kernel<<<FAT_GRID, 512, GEMM_LDS, stream>>>(
        x, W, att_src, att_dst, ei, xp, a_srcv, a_dstv, counts);
    bin_scan_kernel<<<NB, 512, 0, stream>>>(counts, basem, btot);
    bin_append_kernel<<<BIN_BLOCKS, 512, 0, stream>>>(ei, basem, barr);
    fused_gather_kernel<<<NB, 512, 0, stream>>>(barr, btot,
                                                a_srcv, a_dstv, xp, bias, out);
}

// Round 8
// 151.520 us; speedup vs baseline: 1.0683x; 1.0683x over previous
//
#include <hip/hip_runtime.h>
#include <hip/hip_bf16.h>
#include <math.h>

#define N_NODES 50000
#define N_EDGES 1600000
#define IN_DIM  128
#define HC      64   // H*C
#define NH      4    // heads
#define SLOTS   72   // padded CSR slots per node; true max degree ~58
#define NB      1564 // buckets: dst >> 5, 32 nodes each (1564*32 = 50048)
#define BCAP    1280 // per-bucket capacity: mean 1024 + 8 sigma
#define GC_STRIDE 16 // R8: one gcursor per 64B cacheline (was 16/line -> 3.1K
                     // serialized atomic ops per L2 line; now 196/line)
#define GEMM_BLOCKS 391   // 391*128 = 50048 nodes
#define FAT_GRID 587      // 391 gemm + 196 bucket, INTERLEAVED (blockIdx%3==1 -> bucket)
#define FAT_LDS 33792     // max(gemm 64*132*4, bucket 2*NB*4)

// ---------------------------------------------------------------- fat kernel
// R0-proven structure (143.8us): gemm (VALU/LDS-bound) and bucket
// (atomic/latency-bound) blocks CO-RESIDENT from dispatch 0.
__global__ __launch_bounds__(512) void gemm_bucket_kernel(
    const float* __restrict__ x, const float* __restrict__ W,
    const float* __restrict__ att_src, const float* __restrict__ att_dst,
    const int* __restrict__ ei,
    __hip_bfloat16* __restrict__ xp, float* __restrict__ a_src,
    float* __restrict__ a_dst,
    int* __restrict__ gcursor, unsigned int* __restrict__ barr) {
    extern __shared__ char smraw[];
    int tid = (int)threadIdx.x;
    int bx  = (int)blockIdx.x;
    bool is_bucket = (bx % 3) == 1;          // 1,4,...,586: exactly 196 blocks

    if (!is_bucket) {
        // ---- GEMM+logits. gemm block index among non-bucket blocks.
        int gb = bx - (bx + 1) / 3;          // 0..390
        float* Wl = (float*)smraw;
        const float4* W4 = (const float4*)W;
#pragma unroll
        for (int j = 0; j < 4; ++j) {        // 2048 float4 / 512 threads
            int f = j * 512 + tid;
            int c = f >> 5, k4 = f & 31;
            *(float4*)&Wl[c * 132 + k4 * 4] = W4[f];
        }
        __syncthreads();

        int l = tid & 63, w = tid >> 6, q = l >> 4, i = l & 15;
        int n0 = gb * 128 + w * 16 + q * 4;
        int nj[4];
#pragma unroll
        for (int j = 0; j < 4; ++j) {
            int n = n0 + j;
            nj[j] = (n < N_NODES) ? n : N_NODES - 1;   // clamp loads; stores guarded
        }
        const float* wlp = Wl + i * 132;               // rows i,i+16,i+32,i+48
        float4 acc[4] = {{0,0,0,0},{0,0,0,0},{0,0,0,0},{0,0,0,0}};
        float4 xr[4], xn[4];
#pragma unroll
        for (int j = 0; j < 4; ++j) xr[j] = *(const float4*)(x + (size_t)nj[j] * IN_DIM);
#pragma unroll 2
        for (int k0 = 0; k0 < IN_DIM; k0 += 4) {
            if (k0 + 4 < IN_DIM) {
#pragma unroll
                for (int j = 0; j < 4; ++j)
                    xn[j] = *(const float4*)(x + (size_t)nj[j] * IN_DIM + k0 + 4);
            }
            float4 wl0 = *(const float4*)(wlp + 0 * 16 * 132 + k0);
            float4 wl1 = *(const float4*)(wlp + 1 * 16 * 132 + k0);
            float4 wl2 = *(const float4*)(wlp + 2 * 16 * 132 + k0);
            float4 wl3 = *(const float4*)(wlp + 3 * 16 * 132 + k0);
#pragma unroll
            for (int j = 0; j < 4; ++j) {
                float4 xv = xr[j];
                acc[j].x = fmaf(xv.x, wl0.x, fmaf(xv.y, wl0.y, fmaf(xv.z, wl0.z, fmaf(xv.w, wl0.w, acc[j].x))));
                acc[j].y = fmaf(xv.x, wl1.x, fmaf(xv.y, wl1.y, fmaf(xv.z, wl1.z, fmaf(xv.w, wl1.w, acc[j].y))));
                acc[j].z = fmaf(xv.x, wl2.x, fmaf(xv.y, wl2.y, fmaf(xv.z, wl2.z, fmaf(xv.w, wl2.w, acc[j].z))));
                acc[j].w = fmaf(xv.x, wl3.x, fmaf(xv.y, wl3.y, fmaf(xv.z, wl3.z, fmaf(xv.w, wl3.w, acc[j].w))));
            }
#pragma unroll
            for (int j = 0; j < 4; ++j) xr[j] = xn[j];
        }

        float a_s0 = att_src[i], a_s1 = att_src[16 + i], a_s2 = att_src[32 + i], a_s3 = att_src[48 + i];
        float a_d0 = att_dst[i], a_d1 = att_dst[16 + i], a_d2 = att_dst[32 + i], a_d3 = att_dst[48 + i];
#pragma unroll
        for (int j = 0; j < 4; ++j) {
            int n = n0 + j;
            if (n < N_NODES) {                          // quarter-uniform guard
                __hip_bfloat16* xw = xp + (size_t)n * HC;
                xw[i]      = __float2bfloat16(acc[j].x);
                xw[16 + i] = __float2bfloat16(acc[j].y);
                xw[32 + i] = __float2bfloat16(acc[j].z);
                xw[48 + i] = __float2bfloat16(acc[j].w);
                float4 ps, pd;
                ps.x = acc[j].x * a_s0; ps.y = acc[j].y * a_s1;
                ps.z = acc[j].z * a_s2; ps.w = acc[j].w * a_s3;
                pd.x = acc[j].x * a_d0; pd.y = acc[j].y * a_d1;
                pd.z = acc[j].z * a_d2; pd.w = acc[j].w * a_d3;
#pragma unroll
                for (int off = 1; off < 16; off <<= 1) {  // stays within quarter
                    ps.x += __shfl_xor(ps.x, off, 64); ps.y += __shfl_xor(ps.y, off, 64);
                    ps.z += __shfl_xor(ps.z, off, 64); ps.w += __shfl_xor(ps.w, off, 64);
                    pd.x += __shfl_xor(pd.x, off, 64); pd.y += __shfl_xor(pd.y, off, 64);
                    pd.z += __shfl_xor(pd.z, off, 64); pd.w += __shfl_xor(pd.w, off, 64);
                }
                if (i == 0) {
                    *(float4*)(a_src + n * NH) = ps;
                    *(float4*)(a_dst + n * NH) = pd;
                }
            }
        }
    } else {
        // ---- bucket pass. Bin edges by dst>>5; LDS-atomic local
        // positions + one global atomic per bucket per block; packed appends.
        int bb = (bx - 1) / 3;                          // 0..195
        int* lcount = (int*)smraw;
        int* lbase  = lcount + NB;
        for (int j = tid; j < NB; j += 512) lcount[j] = 0;
        __syncthreads();
        int gid = bb * 512 + tid;                       // 16-edge group id
        bool active = gid < N_EDGES / 16;               // NO early return
        int s[16], d[16], b[16], lpos[16];
        if (active) {
            const int4* sp = (const int4*)ei;
            const int4* dp = (const int4*)(ei + N_EDGES);
#pragma unroll
            for (int v = 0; v < 4; ++v) {
                int4 sv = sp[4 * gid + v];
                int4 dv = dp[4 * gid + v];
                s[4*v+0] = sv.x; s[4*v+1] = sv.y; s[4*v+2] = sv.z; s[4*v+3] = sv.w;
                d[4*v+0] = dv.x; d[4*v+1] = dv.y; d[4*v+2] = dv.z; d[4*v+3] = dv.w;
            }
#pragma unroll
            for (int u = 0; u < 16; ++u) {
                b[u] = d[u] >> 5;
                lpos[u] = atomicAdd(&lcount[b[u]], 1);
            }
        }
        __syncthreads();
        for (int j = tid; j < NB; j += 512) {
            int c = lcount[j];
            lbase[j] = (c > 0) ? atomicAdd(&gcursor[j * GC_STRIDE], c) : 0;
        }
        __syncthreads();
        if (active) {
#pragma unroll
            for (int u = 0; u < 16; ++u) {
                int pos = lbase[b[u]] + lpos[u];
                if (pos < BCAP)   // statistically impossible; never corrupt
                    barr[(size_t)b[u] * BCAP + pos] =
                        (unsigned)s[u] | ((unsigned)(d[u] & 31) << 20);
            }
        }
    }
}

// ---------------------------------------------------------------- fused CSR + gather
// R0-proven: 8 dst per wave, 8 lanes/dst, 8 channels/lane (uint4 = 8 bf16);
// phase B covers all 32 bucket nodes in ONE round (4 waves).
__global__ __launch_bounds__(256) void fused_gather_kernel(
    const unsigned int* __restrict__ barr, const int* __restrict__ gcursor,
    const float* __restrict__ a_src, const float* __restrict__ a_dst,
    const __hip_bfloat16* __restrict__ xp, const float* __restrict__ bias,
    float* __restrict__ out) {
    __shared__ int lcsr[32 * SLOTS];   // 9216 B
    __shared__ int deg[32];
    int b = blockIdx.x, tid = (int)threadIdx.x;
    if (tid < 32) deg[tid] = 0;
    __syncthreads();
    int n = gcursor[b * GC_STRIDE];
    n = (n < BCAP) ? n : BCAP;
    const unsigned int* src = barr + (size_t)b * BCAP;

    // ---- phase A: build LDS adjacency (<=1280 records = 2 rounds)
    for (int i0 = 0; i0 < n; i0 += 1024) {
        int ibase = i0 + tid * 4;
        unsigned v[4]; bool val[4]; int dp[4], pos[4];
        if (ibase < n) {
            uint4 r = *(const uint4*)(src + ibase);   // BCAP mult of 4, 16B aligned
            v[0] = r.x; v[1] = r.y; v[2] = r.z; v[3] = r.w;
        } else { v[0] = v[1] = v[2] = v[3] = 0u; }
#pragma unroll
        for (int u = 0; u < 4; ++u) {
            val[u] = (ibase + u) < n;
            dp[u] = (int)(v[u] >> 20);
            if (val[u]) pos[u] = atomicAdd(&deg[dp[u]], 1);
        }
#pragma unroll
        for (int u = 0; u < 4; ++u)
            if (val[u] && pos[u] < SLOTS)
                lcsr[dp[u] * SLOTS + pos[u]] = (int)(v[u] & 0xFFFFF);
    }
    __syncthreads();

    // ---- phase B: one round, 8 dst/wave
    int l = tid & 63;
    int w = tid >> 6;                 // wave 0..3
    int g = l >> 3;                   // group 0..7 (8 lanes each)
    int i = l & 7;                    // lane within group
    int h = i >> 1;                   // head of this lane's 8 channels
    int dl = w * 8 + g;               // local node 0..31
    int dst = (b << 5) + dl;
    int dg = deg[dl];
    dg = (dg < SLOTS) ? dg : SLOTS;
    // dst in [50000,50048): a_dst read lands inside ws (pad region); value
    // unused (dg==0) and the store is guarded.
    float adh = a_dst[dst * NH + h];

    int sreg[9];
#pragma unroll
    for (int k = 0; k < 9; ++k) sreg[k] = lcsr[dl * SLOTS + k * 8 + i];

    const unsigned short* xpi = (const unsigned short*)xp + 8 * i;  // lane's 8 ch
    const float* asrch = a_src + h;
    int gsel = l & 56;                // group base lane for shfl
    float a0=0,a1=0,a2=0,a3=0,a4=0,a5=0,a6=0,a7=0;
    float dsum = 0.f;

#pragma unroll
    for (int k = 0; k < 9; ++k) {
        if (dg > k * 8) {             // group-uniform; exec-mask guard
            int cnt = dg - k * 8;
            int reg = sreg[k];
            int s8[8]; float g8[8]; uint4 t8[8];
#pragma unroll
            for (int u = 0; u < 8; ++u) {
                int raw = __shfl(reg, gsel | u, 64);
                s8[u] = (u < cnt) ? raw : 0;          // safe dummy idx
            }
#pragma unroll
            for (int u = 0; u < 8; ++u) g8[u] = asrch[s8[u] * NH];
#pragma unroll
            for (int u = 0; u < 8; ++u)
                t8[u] = *(const uint4*)(xpi + (size_t)s8[u] * HC);
#pragma unroll
            for (int u = 0; u < 8; ++u) {
                float e = g8[u] + adh;
                e = fmaxf(e, 0.2f * e);
                float wv = (u < cnt) ? __expf(e) : 0.f;
                dsum += wv;
                uint4 t = t8[u];
                a0 = fmaf(wv, __uint_as_float(t.x << 16),          a0);
                a1 = fmaf(wv, __uint_as_float(t.x & 0xffff0000u),  a1);
                a2 = fmaf(wv, __uint_as_float(t.y << 16),          a2);
                a3 = fmaf(wv, __uint_as_float(t.y & 0xffff0000u),  a3);
                a4 = fmaf(wv, __uint_as_float(t.z << 16),          a4);
                a5 = fmaf(wv, __uint_as_float(t.z & 0xffff0000u),  a5);
                a6 = fmaf(wv, __uint_as_float(t.w << 16),          a6);
                a7 = fmaf(wv, __uint_as_float(t.w & 0xffff0000u),  a7);
            }
        }
    }
    if (dst < N_NODES) {
        float inv = 1.f / (dsum + 1e-16f);
        float4 b0 = *(const float4*)(bias + 8 * i);
        float4 b1 = *(const float4*)(bias + 8 * i + 4);
        float4 o0, o1;
        o0.x = a0 * inv + b0.x; o0.y = a1 * inv + b0.y;
        o0.z = a2 * inv + b0.z; o0.w = a3 * inv + b0.w;
        o1.x = a4 * inv + b1.x; o1.y = a5 * inv + b1.y;
        o1.z = a6 * inv + b1.z; o1.w = a7 * inv + b1.w;
        float* op = out + (size_t)dst * HC + 8 * i;
        *(float4*)op = o0;
        *(float4*)(op + 4) = o1;
    }
}

// ---------------------------------------------------------------- launcher
extern "C" void kernel_launch(void* const* d_in, const int* in_sizes, int n_in,
                              void* d_out, int out_size, void* d_ws, size_t ws_size,
                              hipStream_t stream) {
    const float* x       = (const float*)d_in[0];
    const int*   ei      = (const int*)d_in[1];   // [2][E]
    const float* W       = (const float*)d_in[2];
    const float* att_src = (const float*)d_in[3];
    const float* att_dst = (const float*)d_in[4];
    const float* bias    = (const float*)d_in[5];
    float* out = (float*)d_out;

    char* ws = (char*)d_ws;
    __hip_bfloat16* xp      = (__hip_bfloat16*)(ws);   //  6,400,000 B
    float*          a_srcv  = (float*)(ws + 6400000);  //    800,000 B
    float*          a_dstv  = (float*)(ws + 7200000);  //    800,000 B
    // pad [8.0M, 8.016M): absorbs guarded a_dst reads for dst in [50000,50048)
    int*            gcursor = (int*)  (ws + 8016384);  // 1564*16*4 = 100,096 B
    unsigned int*   barr    = (unsigned int*)(ws + 8120320); // 8,007,680 B
    // total ~16.1 MB

    hipMemsetAsync(gcursor, 0, NB * GC_STRIDE * sizeof(int), stream);
    gemm_bucket_kernel<<<FAT_GRID, 512, FAT_LDS, stream>>>(
        x, W, att_src, att_dst, ei, xp, a_srcv, a_dstv, gcursor, barr);
    fused_gather_kernel<<<NB, 256, 0, stream>>>(barr, gcursor,
                                                a_srcv, a_dstv, xp, bias, out);
}